// Round 1
// baseline (982.116 us; speedup 1.0000x reference)
//
#include <hip/hip_runtime.h>
#include <stdint.h>

#define B_ 4
#define N_ 4096
#define C1_ 58
#define K_ 32
#define EPS_ 1e-5f
#define PTS 16

static __device__ __forceinline__ float bf2f(unsigned short u){
  return __uint_as_float(((unsigned int)u) << 16);
}
static __device__ __forceinline__ unsigned short f2bf(float f){
  unsigned int x = __float_as_uint(f);
  x = (x + 0x7FFFu + ((x >> 16) & 1u)) >> 16;
  return (unsigned short)x;
}

// ---------------- ball query ----------------
// reference: keep indices j (ascending) with sq <= r^2, first K, pad with first.
__global__ __launch_bounds__(64) void ball_kernel(const float* __restrict__ xyz,
                                                  int* __restrict__ inds){
  int tid = blockIdx.x * 64 + threadIdx.x;      // over B*N
  int b = tid >> 12;                            // N_=4096
  int n = tid & (N_ - 1);
  const float* xb = xyz + (size_t)b * N_ * 3;
  float qx = xb[n*3+0], qy = xb[n*3+1], qz = xb[n*3+2];
  const float R2 = (float)(0.3 * 0.3);          // matches python radius*radius -> f32
  int* outp = inds + (size_t)tid * K_;
  int cnt = 0, first = 0;
  for (int j = 0; j < N_; ++j){
    float dx = xb[j*3+0] - qx;
    float dy = xb[j*3+1] - qy;
    float dz = xb[j*3+2] - qz;
    // exact f32 ((dx*dx + dy*dy) + dz*dz), no fma contraction
    float s = __fadd_rn(__fadd_rn(__fmul_rn(dx,dx), __fmul_rn(dy,dy)), __fmul_rn(dz,dz));
    if (s <= R2){
      if (cnt == 0) first = j;
      outp[cnt] = j;
      if (++cnt == K_) break;
    }
  }
  for (; cnt < K_; ++cnt) outp[cnt] = first;
}

// ---------------- fused conv layer ----------------
// MODE_IN : 0 = gather new_points (center|nbr-center|feature), 1 = load bf16 x, apply GN(stats_in)+relu
// MODE_OUT: 0 = store raw bf16 + accumulate group stats, 1 = stats only, 2 = GN(stats_out)+relu+max_k -> out
template<int COUT, int MODE_IN, int MODE_OUT>
__global__ __launch_bounds__(256)
void conv_kernel(const float* __restrict__ feature, const float* __restrict__ xyz,
                 const int* __restrict__ inds,
                 const unsigned short* __restrict__ xin, const float* __restrict__ mr_in,
                 const float* __restrict__ gin, const float* __restrict__ bin,
                 const float* __restrict__ Wg,
                 unsigned short* __restrict__ xout, float* __restrict__ sums,
                 const float* __restrict__ mr_out, const float* __restrict__ gout,
                 const float* __restrict__ bout, float* __restrict__ out)
{
  __shared__ float4 Wl[COUT][16];               // W[c4 xor-swizzled by o]
  __shared__ float4 inl[K_][16];                // in[k][c] as float4
  __shared__ int   sidx[K_];
  __shared__ float red[(MODE_OUT==2)?4:1][(MODE_OUT==2)?128:1];
  __shared__ float omax[(MODE_OUT==2)?PTS:1][(MODE_OUT==2)?128:1];

  const int t = threadIdx.x;
  const int bid = blockIdx.x;
  const int b = bid / (N_ / PTS);
  const int n0 = (bid % (N_ / PTS)) * PTS;

  // stage W into LDS, float4 chunks swizzled: chunk c4 stored at c4 ^ (o&15)
  const float4* Wg4 = (const float4*)Wg;
  for (int i = t; i < COUT * 16; i += 256){
    int oo = i >> 4, c4 = i & 15;
    Wl[oo][c4 ^ (oo & 15)] = Wg4[i];
  }

  const int w = t >> 6;          // wave id: k rows {w, w+4, ..., w+28}
  const int o = t & 63;          // output channel (and o+64 for COUT=128)
  const int kt = t >> 3;         // staging row
  const int ci = t & 7;          // staging 8-col chunk

  float sA = 0.f, s2A = 0.f, sB = 0.f, s2B = 0.f;

  // final-pass per-lane constants
  float meanA=0.f, rstdA=0.f, meanB=0.f, rstdB=0.f, gA_=0.f, bA_=0.f, gB_=0.f, bB_=0.f;
  if constexpr (MODE_OUT == 2){
    int ga = o >> 5, gb = ga + 2;
    meanA = mr_out[(b*4+ga)*2+0]; rstdA = mr_out[(b*4+ga)*2+1];
    meanB = mr_out[(b*4+gb)*2+0]; rstdB = mr_out[(b*4+gb)*2+1];
    gA_ = gout[o];    bA_ = bout[o];
    gB_ = gout[o+64]; bB_ = bout[o+64];
  }

  for (int p = 0; p < PTS; ++p){
    const int n = n0 + p;
    const size_t bn = (size_t)b * N_ + n;

    __syncthreads();   // previous iter's compute done with inl/red; W visible after 1st

    // ---- stage input rows into inl[k][c] ----
    if constexpr (MODE_IN == 0){
      if (t < K_) sidx[t] = inds[bn * K_ + t];
      __syncthreads();
      float c0v = xyz[bn*3+0], c1v = xyz[bn*3+1], c2v = xyz[bn*3+2];
      int idx = sidx[kt];
      const float* frow = feature + ((size_t)b * N_ + idx) * C1_;
      float v[8];
      #pragma unroll
      for (int j = 0; j < 8; ++j){
        int c = ci * 8 + j;
        float val;
        if (c < 3){
          val = (c == 0) ? c0v : ((c == 1) ? c1v : c2v);
        } else if (c < 6){
          float nc = xyz[((size_t)b * N_ + idx) * 3 + (c - 3)];
          float cc = (c == 3) ? c0v : ((c == 4) ? c1v : c2v);
          val = nc - cc;
        } else {
          val = frow[c - 6];
        }
        v[j] = val;
      }
      inl[kt][ci*2+0] = make_float4(v[0], v[1], v[2], v[3]);
      inl[kt][ci*2+1] = make_float4(v[4], v[5], v[6], v[7]);
    } else {
      uint4 raw = ((const uint4*)xin)[bn * K_ * 8 + (size_t)kt * 8 + ci];
      const unsigned short* u = (const unsigned short*)&raw;
      float v[8];
      #pragma unroll
      for (int j = 0; j < 8; ++j){
        int c = ci * 8 + j;
        int g = c >> 5;
        float mean = mr_in[(b*4+g)*2+0], rstd = mr_in[(b*4+g)*2+1];
        float x = bf2f(u[j]);
        float xn = (x - mean) * rstd * gin[c] + bin[c];
        v[j] = xn > 0.f ? xn : 0.f;
      }
      inl[kt][ci*2+0] = make_float4(v[0], v[1], v[2], v[3]);
      inl[kt][ci*2+1] = make_float4(v[4], v[5], v[6], v[7]);
    }
    __syncthreads();

    // ---- compute y[k][o] = sum_c in[k][c]*W[o][c] for k in {w,w+4,...} ----
    float acc[8];
    float accB[8];
    #pragma unroll
    for (int i = 0; i < 8; ++i){ acc[i] = 0.f; accB[i] = 0.f; }

    #pragma unroll
    for (int c4 = 0; c4 < 16; ++c4){
      const int c4s = c4 ^ (o & 15);
      float4 wv = Wl[o][c4s];
      float4 wv2;
      if constexpr (COUT == 128) wv2 = Wl[o + 64][c4s];
      #pragma unroll
      for (int kk = 0; kk < 8; ++kk){
        float4 a = inl[w + kk*4][c4];
        acc[kk] = fmaf(a.x, wv.x, fmaf(a.y, wv.y, fmaf(a.z, wv.z, fmaf(a.w, wv.w, acc[kk]))));
        if constexpr (COUT == 128)
          accB[kk] = fmaf(a.x, wv2.x, fmaf(a.y, wv2.y, fmaf(a.z, wv2.z, fmaf(a.w, wv2.w, accB[kk]))));
      }
    }

    if constexpr (MODE_OUT == 0 || MODE_OUT == 1){
      #pragma unroll
      for (int kk = 0; kk < 8; ++kk){
        float y = acc[kk]; sA += y; s2A = fmaf(y, y, s2A);
        if constexpr (COUT == 128){ float z = accB[kk]; sB += z; s2B = fmaf(z, z, s2B); }
      }
      if constexpr (MODE_OUT == 0){
        #pragma unroll
        for (int kk = 0; kk < 8; ++kk){
          int k = w + kk*4;
          xout[(bn * K_ + k) * COUT + o] = f2bf(acc[kk]);
          if constexpr (COUT == 128)
            xout[(bn * K_ + k) * COUT + o + 64] = f2bf(accB[kk]);
        }
      }
    } else {
      // normalize + relu + per-lane max over k
      float mA = -1e30f, mB = -1e30f;
      #pragma unroll
      for (int kk = 0; kk < 8; ++kk){
        float vA = (acc[kk]  - meanA) * rstdA * gA_ + bA_; vA = vA > 0.f ? vA : 0.f; mA = fmaxf(mA, vA);
        float vB = (accB[kk] - meanB) * rstdB * gB_ + bB_; vB = vB > 0.f ? vB : 0.f; mB = fmaxf(mB, vB);
      }
      red[w][o]      = mA;
      red[w][o + 64] = mB;
      __syncthreads();
      if (t < 128){
        float m = fmaxf(fmaxf(red[0][t], red[1][t]), fmaxf(red[2][t], red[3][t]));
        omax[p][t] = m;
      }
    }
  }

  // ---- epilogue ----
  if constexpr (MODE_OUT == 0 || MODE_OUT == 1){
    // reduce within each 32-lane half (channels group g = o>>5)
    #pragma unroll
    for (int off = 16; off > 0; off >>= 1){
      sA  += __shfl_down(sA,  off, 32);
      s2A += __shfl_down(s2A, off, 32);
      if constexpr (COUT == 128){
        sB  += __shfl_down(sB,  off, 32);
        s2B += __shfl_down(s2B, off, 32);
      }
    }
    if ((t & 31) == 0){
      int g = o >> 5;   // 0 for lanes 0-31, 1 for lanes 32-63
      atomicAdd(&sums[(b*4+g)*2+0], sA);
      atomicAdd(&sums[(b*4+g)*2+1], s2A);
      if constexpr (COUT == 128){
        atomicAdd(&sums[(b*4+g+2)*2+0], sB);
        atomicAdd(&sums[(b*4+g+2)*2+1], s2B);
      }
    }
  }
  if constexpr (MODE_OUT == 2){
    __syncthreads();
    int oo = t >> 1;
    int p0 = (t & 1) * 8;
    float* orow = out + ((size_t)b * 128 + oo) * N_ + n0 + p0;
    #pragma unroll
    for (int j = 0; j < 8; ++j) orow[j] = omax[p0 + j][oo];
  }
}

// ---------------- stats finalize ----------------
__global__ void finalize_kernel(const float* __restrict__ sums, float* __restrict__ mr, int ng){
  int t = blockIdx.x * blockDim.x + threadIdx.x;
  if (t < ng){
    const float cnt = 4194304.f;   // 32 ch * K * N
    float s = sums[t*2+0], s2 = sums[t*2+1];
    float mean = s / cnt;
    float var = s2 / cnt - mean * mean;
    float rstd = 1.f / sqrtf(var + EPS_);
    mr[t*2+0] = mean;
    mr[t*2+1] = rstd;
  }
}

extern "C" void kernel_launch(void* const* d_in, const int* in_sizes, int n_in,
                              void* d_out, int out_size, void* d_ws, size_t ws_size,
                              hipStream_t stream) {
  const float* feature = (const float*)d_in[0];
  const float* xyz     = (const float*)d_in[1];
  const float* W0 = (const float*)d_in[2];
  const float* g0 = (const float*)d_in[3];
  const float* b0 = (const float*)d_in[4];
  const float* W1 = (const float*)d_in[5];
  const float* g1 = (const float*)d_in[6];
  const float* b1 = (const float*)d_in[7];
  const float* W2 = (const float*)d_in[8];
  const float* g2 = (const float*)d_in[9];
  const float* b2 = (const float*)d_in[10];
  float* out = (float*)d_out;

  char* ws = (char*)d_ws;
  const size_t INDS_BYTES = (size_t)B_ * N_ * K_ * sizeof(int);   // 2 MiB
  const size_t XBYTES     = (size_t)B_ * N_ * K_ * 64 * 2;        // 64 MiB each
  int* inds           = (int*)ws;
  unsigned short* x0  = (unsigned short*)(ws + INDS_BYTES);
  unsigned short* x1  = (unsigned short*)(ws + INDS_BYTES + XBYTES);
  float* sums         = (float*)(ws + INDS_BYTES + 2 * XBYTES);   // [3][B][4][2]
  float* mr           = sums + 3 * 32;                            // [3][B][4][2]

  hipMemsetAsync(sums, 0, 3 * 32 * sizeof(float), stream);

  ball_kernel<<<B_ * N_ / 64, 64, 0, stream>>>(xyz, inds);

  const int grid = B_ * N_ / PTS;

  // layer 0: gather -> conv -> store raw bf16 + stats
  conv_kernel<64, 0, 0><<<grid, 256, 0, stream>>>(
      feature, xyz, inds,
      nullptr, nullptr, nullptr, nullptr,
      W0, x0, sums + 0,
      nullptr, nullptr, nullptr, nullptr);
  finalize_kernel<<<1, 32, 0, stream>>>(sums + 0, mr + 0, 16);

  // layer 1: gn0+relu on x0 -> conv -> store raw bf16 + stats
  conv_kernel<64, 1, 0><<<grid, 256, 0, stream>>>(
      nullptr, nullptr, nullptr,
      x0, mr + 0, g0, b0,
      W1, x1, sums + 32,
      nullptr, nullptr, nullptr, nullptr);
  finalize_kernel<<<1, 32, 0, stream>>>(sums + 32, mr + 32, 16);

  // layer 2 pass A: gn1+relu on x1 -> conv -> stats only
  conv_kernel<128, 1, 1><<<grid, 256, 0, stream>>>(
      nullptr, nullptr, nullptr,
      x1, mr + 32, g1, b1,
      W2, nullptr, sums + 64,
      nullptr, nullptr, nullptr, nullptr);
  finalize_kernel<<<1, 32, 0, stream>>>(sums + 64, mr + 64, 16);

  // layer 2 pass B: recompute conv -> gn2+relu -> max over k -> out
  conv_kernel<128, 1, 2><<<grid, 256, 0, stream>>>(
      nullptr, nullptr, nullptr,
      x1, mr + 32, g1, b1,
      W2, nullptr, nullptr,
      mr + 64, g2, b2, out);
}

// Round 2
// 626.911 us; speedup vs baseline: 1.5666x; 1.5666x over previous
//
#include <hip/hip_runtime.h>
#include <stdint.h>

#define B_ 4
#define N_ 4096
#define C1_ 58
#define K_ 32
#define EPS_ 1e-5f
#define PTS 16

static __device__ __forceinline__ float bf2f(unsigned short u){
  return __uint_as_float(((unsigned int)u) << 16);
}
static __device__ __forceinline__ unsigned short f2bf(float f){
  unsigned int x = __float_as_uint(f);
  x = (x + 0x7FFFu + ((x >> 16) & 1u)) >> 16;
  return (unsigned short)x;
}

// ---------------- ball query (wave-parallel) ----------------
// One 64-lane wave per query. Lanes test 64 candidates/iter; ballot +
// prefix-popcount emits in-radius indices in ascending order; early exit at K.
__global__ __launch_bounds__(256) void ball_kernel(const float* __restrict__ xyz,
                                                   int* __restrict__ inds){
  const int wid  = (blockIdx.x * 256 + threadIdx.x) >> 6;   // query id over B*N
  const int lane = threadIdx.x & 63;
  const int b = wid >> 12;                                  // N_=4096
  const int n = wid & (N_ - 1);
  const float* xb = xyz + (size_t)b * N_ * 3;
  const float qx = xb[n*3+0], qy = xb[n*3+1], qz = xb[n*3+2];
  const float R2 = (float)(0.3 * 0.3);
  int* outp = inds + (size_t)wid * K_;
  int cnt = 0;
  int first = -1;
  for (int j0 = 0; j0 < N_ && cnt < K_; j0 += 64){
    const int j = j0 + lane;
    float dx = xb[j*3+0] - qx;
    float dy = xb[j*3+1] - qy;
    float dz = xb[j*3+2] - qz;
    // exact f32 ((dx*dx + dy*dy) + dz*dz), no fma contraction (matches numpy)
    float s = __fadd_rn(__fadd_rn(__fmul_rn(dx,dx), __fmul_rn(dy,dy)), __fmul_rn(dz,dz));
    bool p = (s <= R2);
    unsigned long long mask = __ballot(p);
    if (p){
      int pos = cnt + __popcll(mask & ((1ull << lane) - 1ull));
      if (pos < K_) outp[pos] = j;
    }
    if (first < 0 && mask) first = j0 + __builtin_ctzll(mask);
    cnt += __popcll(mask);
  }
  if (lane < K_ && lane >= cnt) outp[lane] = first;   // pad with first hit
}

// ---------------- fused conv layer ----------------
// MODE_IN : 0 = gather new_points (center|nbr-center|feature), 1 = load bf16 x, apply GN(mr_in)+relu
// MODE_OUT: 0 = store raw bf16 + accumulate group stats
//           2 = accumulate group stats + per-(n,o) max/min over k -> ymax/ymin
template<int COUT, int MODE_IN, int MODE_OUT>
__global__ __launch_bounds__(256)
void conv_kernel(const float* __restrict__ feature, const float* __restrict__ xyz,
                 const int* __restrict__ inds,
                 const unsigned short* __restrict__ xin, const float* __restrict__ mr_in,
                 const float* __restrict__ gin, const float* __restrict__ bin,
                 const float* __restrict__ Wg,
                 unsigned short* __restrict__ xout, float* __restrict__ sums,
                 float* __restrict__ ymax, float* __restrict__ ymin)
{
  __shared__ float4 Wl[COUT][16];               // W rows, float4 chunks xor-swizzled by o
  __shared__ float4 inl[K_][16];                // in[k][c] as float4
  __shared__ int   sidx[K_];
  __shared__ float redmax[(MODE_OUT==2)?4:1][(MODE_OUT==2)?128:1];
  __shared__ float redmin[(MODE_OUT==2)?4:1][(MODE_OUT==2)?128:1];
  __shared__ float omax[(MODE_OUT==2)?PTS:1][(MODE_OUT==2)?128:1];
  __shared__ float omin[(MODE_OUT==2)?PTS:1][(MODE_OUT==2)?128:1];

  const int t = threadIdx.x;
  const int bid = blockIdx.x;
  const int b = bid / (N_ / PTS);
  const int n0 = (bid % (N_ / PTS)) * PTS;

  const float4* Wg4 = (const float4*)Wg;
  for (int i = t; i < COUT * 16; i += 256){
    int oo = i >> 4, c4 = i & 15;
    Wl[oo][c4 ^ (oo & 15)] = Wg4[i];
  }

  const int w = t >> 6;          // wave id: owns k rows {w, w+4, ..., w+28}
  const int o = t & 63;          // output channel (and o+64 for COUT=128)
  const int kt = t >> 3;         // staging row
  const int ci = t & 7;          // staging 8-col chunk

  float sA = 0.f, s2A = 0.f, sB = 0.f, s2B = 0.f;

  for (int p = 0; p < PTS; ++p){
    const int n = n0 + p;
    const size_t bn = (size_t)b * N_ + n;

    __syncthreads();   // prev iter done with inl/red; W visible after 1st

    // ---- stage input rows into inl[k][c] ----
    if constexpr (MODE_IN == 0){
      if (t < K_) sidx[t] = inds[bn * K_ + t];
      __syncthreads();
      float c0v = xyz[bn*3+0], c1v = xyz[bn*3+1], c2v = xyz[bn*3+2];
      int idx = sidx[kt];
      const float* frow = feature + ((size_t)b * N_ + idx) * C1_;
      float v[8];
      #pragma unroll
      for (int j = 0; j < 8; ++j){
        int c = ci * 8 + j;
        float val;
        if (c < 3){
          val = (c == 0) ? c0v : ((c == 1) ? c1v : c2v);
        } else if (c < 6){
          float nc = xyz[((size_t)b * N_ + idx) * 3 + (c - 3)];
          float cc = (c == 3) ? c0v : ((c == 4) ? c1v : c2v);
          val = nc - cc;
        } else {
          val = frow[c - 6];
        }
        v[j] = val;
      }
      inl[kt][ci*2+0] = make_float4(v[0], v[1], v[2], v[3]);
      inl[kt][ci*2+1] = make_float4(v[4], v[5], v[6], v[7]);
    } else {
      uint4 raw = ((const uint4*)xin)[bn * K_ * 8 + (size_t)kt * 8 + ci];
      const unsigned short* u = (const unsigned short*)&raw;
      float v[8];
      #pragma unroll
      for (int j = 0; j < 8; ++j){
        int c = ci * 8 + j;
        int g = c >> 5;
        float mean = mr_in[(b*4+g)*2+0], rstd = mr_in[(b*4+g)*2+1];
        float x = bf2f(u[j]);
        float xn = (x - mean) * rstd * gin[c] + bin[c];
        v[j] = xn > 0.f ? xn : 0.f;
      }
      inl[kt][ci*2+0] = make_float4(v[0], v[1], v[2], v[3]);
      inl[kt][ci*2+1] = make_float4(v[4], v[5], v[6], v[7]);
    }
    __syncthreads();

    // ---- y[k][o] = sum_c in[k][c]*W[o][c], k in {w, w+4, ..., w+28} ----
    float acc[8];
    float accB[8];
    #pragma unroll
    for (int i = 0; i < 8; ++i){ acc[i] = 0.f; accB[i] = 0.f; }

    #pragma unroll
    for (int c4 = 0; c4 < 16; ++c4){
      const int c4s = c4 ^ (o & 15);
      float4 wv = Wl[o][c4s];
      float4 wv2;
      if constexpr (COUT == 128) wv2 = Wl[o + 64][c4s];
      #pragma unroll
      for (int kk = 0; kk < 8; ++kk){
        float4 a = inl[w + kk*4][c4];
        acc[kk] = fmaf(a.x, wv.x, fmaf(a.y, wv.y, fmaf(a.z, wv.z, fmaf(a.w, wv.w, acc[kk]))));
        if constexpr (COUT == 128)
          accB[kk] = fmaf(a.x, wv2.x, fmaf(a.y, wv2.y, fmaf(a.z, wv2.z, fmaf(a.w, wv2.w, accB[kk]))));
      }
    }

    // ---- stats (all modes) ----
    #pragma unroll
    for (int kk = 0; kk < 8; ++kk){
      float y = acc[kk]; sA += y; s2A = fmaf(y, y, s2A);
      if constexpr (COUT == 128){ float z = accB[kk]; sB += z; s2B = fmaf(z, z, s2B); }
    }

    if constexpr (MODE_OUT == 0){
      #pragma unroll
      for (int kk = 0; kk < 8; ++kk){
        int k = w + kk*4;
        xout[(bn * K_ + k) * COUT + o] = f2bf(acc[kk]);
        if constexpr (COUT == 128)
          xout[(bn * K_ + k) * COUT + o + 64] = f2bf(accB[kk]);
      }
    } else {
      // raw-y max/min over this wave's 8 k rows
      float mA = -1e30f, nA = 1e30f, mB = -1e30f, nB = 1e30f;
      #pragma unroll
      for (int kk = 0; kk < 8; ++kk){
        mA = fmaxf(mA, acc[kk]);  nA = fminf(nA, acc[kk]);
        mB = fmaxf(mB, accB[kk]); nB = fminf(nB, accB[kk]);
      }
      redmax[w][o]      = mA; redmin[w][o]      = nA;
      redmax[w][o + 64] = mB; redmin[w][o + 64] = nB;
      __syncthreads();
      if (t < 128){
        omax[p][t] = fmaxf(fmaxf(redmax[0][t], redmax[1][t]), fmaxf(redmax[2][t], redmax[3][t]));
        omin[p][t] = fminf(fminf(redmin[0][t], redmin[1][t]), fminf(redmin[2][t], redmin[3][t]));
      }
    }
  }

  // ---- epilogue: group-stats reduce + atomics ----
  #pragma unroll
  for (int off = 16; off > 0; off >>= 1){
    sA  += __shfl_down(sA,  off, 32);
    s2A += __shfl_down(s2A, off, 32);
    if constexpr (COUT == 128){
      sB  += __shfl_down(sB,  off, 32);
      s2B += __shfl_down(s2B, off, 32);
    }
  }
  if ((t & 31) == 0){
    int g = o >> 5;   // 0 for lanes 0-31, 1 for lanes 32-63
    atomicAdd(&sums[(b*4+g)*2+0], sA);
    atomicAdd(&sums[(b*4+g)*2+1], s2A);
    if constexpr (COUT == 128){
      atomicAdd(&sums[(b*4+g+2)*2+0], sB);
      atomicAdd(&sums[(b*4+g+2)*2+1], s2B);
    }
  }

  if constexpr (MODE_OUT == 2){
    __syncthreads();
    int oo = t >> 1;
    int p0 = (t & 1) * 8;
    float* mrow = ymax + ((size_t)b * 128 + oo) * N_ + n0 + p0;
    float* nrow = ymin + ((size_t)b * 128 + oo) * N_ + n0 + p0;
    #pragma unroll
    for (int j = 0; j < 8; ++j){
      mrow[j] = omax[p0 + j][oo];
      nrow[j] = omin[p0 + j][oo];
    }
  }
}

// ---------------- stats finalize ----------------
__global__ void finalize_kernel(const float* __restrict__ sums, float* __restrict__ mr, int ng){
  int t = blockIdx.x * blockDim.x + threadIdx.x;
  if (t < ng){
    const float cnt = 4194304.f;   // 32 ch * K * N
    float s = sums[t*2+0], s2 = sums[t*2+1];
    float mean = s / cnt;
    float var = s2 / cnt - mean * mean;
    float rstd = 1.f / sqrtf(var + EPS_);
    mr[t*2+0] = mean;
    mr[t*2+1] = rstd;
  }
}

// ---------------- final GN+relu on the k-extremum ----------------
// out = relu(slope*y + c) is monotone in y; pick max (slope>=0) or min (slope<0).
__global__ __launch_bounds__(256)
void out_kernel(const float* __restrict__ ymax, const float* __restrict__ ymin,
                const float* __restrict__ mr, const float* __restrict__ g2,
                const float* __restrict__ b2, float* __restrict__ out){
  int i = blockIdx.x * 256 + threadIdx.x;       // over B*128*N, layout [b][o][n]
  int b = i >> 19;                              // 128*4096 = 2^19
  int o = (i >> 12) & 127;
  int g = o >> 5;
  float mean = mr[(b*4+g)*2+0], rstd = mr[(b*4+g)*2+1];
  float gm = g2[o], bt = b2[o];
  float slope = rstd * gm;
  float y = (slope >= 0.f) ? ymax[i] : ymin[i];
  float v = (y - mean) * rstd * gm + bt;
  out[i] = v > 0.f ? v : 0.f;
}

extern "C" void kernel_launch(void* const* d_in, const int* in_sizes, int n_in,
                              void* d_out, int out_size, void* d_ws, size_t ws_size,
                              hipStream_t stream) {
  const float* feature = (const float*)d_in[0];
  const float* xyz     = (const float*)d_in[1];
  const float* W0 = (const float*)d_in[2];
  const float* g0 = (const float*)d_in[3];
  const float* b0 = (const float*)d_in[4];
  const float* W1 = (const float*)d_in[5];
  const float* g1 = (const float*)d_in[6];
  const float* b1 = (const float*)d_in[7];
  const float* W2 = (const float*)d_in[8];
  const float* g2 = (const float*)d_in[9];
  const float* b2 = (const float*)d_in[10];
  float* out = (float*)d_out;

  char* ws = (char*)d_ws;
  const size_t INDS_BYTES = (size_t)B_ * N_ * K_ * sizeof(int);   // 2 MiB
  const size_t XBYTES     = (size_t)B_ * N_ * K_ * 64 * 2;        // 64 MiB each
  const size_t YBYTES     = (size_t)B_ * 128 * N_ * sizeof(float);// 8 MiB each
  int* inds           = (int*)ws;
  unsigned short* x1  = (unsigned short*)(ws + INDS_BYTES);               // [2, 66) MiB
  unsigned short* x0  = (unsigned short*)(ws + INDS_BYTES + XBYTES);      // [66,130) MiB
  float* ymax         = (float*)(ws + INDS_BYTES + XBYTES);              // overlaps dead x0
  float* ymin         = (float*)(ws + INDS_BYTES + XBYTES + YBYTES);
  float* sums         = (float*)(ws + INDS_BYTES + 2 * XBYTES);          // [3][B][4][2]
  float* mr           = sums + 3 * 32;                                   // [3][B][4][2]

  hipMemsetAsync(sums, 0, 3 * 32 * sizeof(float), stream);

  ball_kernel<<<B_ * N_ / 4, 256, 0, stream>>>(xyz, inds);   // 1 wave / query

  const int grid = B_ * N_ / PTS;

  // layer 0: gather -> conv -> store raw bf16 x0 + stats
  conv_kernel<64, 0, 0><<<grid, 256, 0, stream>>>(
      feature, xyz, inds,
      nullptr, nullptr, nullptr, nullptr,
      W0, x0, sums + 0, nullptr, nullptr);
  finalize_kernel<<<1, 32, 0, stream>>>(sums + 0, mr + 0, 16);

  // layer 1: gn0+relu on x0 -> conv -> store raw bf16 x1 + stats
  conv_kernel<64, 1, 0><<<grid, 256, 0, stream>>>(
      nullptr, nullptr, nullptr,
      x0, mr + 0, g0, b0,
      W1, x1, sums + 32, nullptr, nullptr);
  finalize_kernel<<<1, 32, 0, stream>>>(sums + 32, mr + 32, 16);

  // layer 2 (single pass): gn1+relu on x1 -> conv128 -> stats + max/min over k
  conv_kernel<128, 1, 2><<<grid, 256, 0, stream>>>(
      nullptr, nullptr, nullptr,
      x1, mr + 32, g1, b1,
      W2, nullptr, sums + 64, ymax, ymin);
  finalize_kernel<<<1, 32, 0, stream>>>(sums + 64, mr + 64, 16);

  // final: GN+relu applied to the k-extremum
  out_kernel<<<(B_ * 128 * N_) / 256, 256, 0, stream>>>(ymax, ymin, mr + 64, g2, b2, out);
}